// Round 10
// baseline (736.186 us; speedup 1.0000x reference)
//
#include <hip/hip_runtime.h>
#include <hip/hip_bf16.h>

#define N_TOK 16384
#define DDIM  512
#define HDIM  1024
#define ODIM  512
#define NG    3
#define NE    4
#define NGE   12
#define TASK_CAP 544   // BM=64 tiles: worst case 512+11, rounded to 68*8

typedef __bf16 bf16x8 __attribute__((ext_vector_type(8)));
typedef float  f32x4  __attribute__((ext_vector_type(4)));

// ---------------- workspace layout (bytes) ----------------
static constexpr size_t OFF_WSLOT = 512;                               // N*2 floats
static constexpr size_t OFF_ELIST = OFF_WSLOT + (size_t)N_TOK*2*4;     // 12*N ints
static constexpr size_t OFF_TASK  = 917504;                            // int2[TASK_CAP]
static constexpr size_t OFF_XBF   = 1048576;                           // N*D bf16
static constexpr size_t OFF_W1    = OFF_XBF + (size_t)N_TOK*DDIM*2;
static constexpr size_t OFF_W2    = OFF_W1  + (size_t)NGE*HDIM*DDIM*2;
static constexpr size_t OFF_WP    = OFF_W2  + (size_t)NGE*HDIM*HDIM*2;
static constexpr size_t OFF_W3    = OFF_WP  + (size_t)NGE*HDIM*DDIM*2;
static constexpr size_t OFF_Y     = OFF_W3  + (size_t)NGE*ODIM*HDIM*2;
static constexpr size_t WS_NEED   = OFF_Y   + (size_t)N_TOK*2*ODIM*2;

// ---------------- cast fp32 -> bf16 ----------------
__global__ void cast_all_k(const float* __restrict__ x,  const float* __restrict__ w1,
                           const float* __restrict__ w2, const float* __restrict__ wp,
                           const float* __restrict__ w3,
                           __bf16* xbf, __bf16* w1b, __bf16* w2b, __bf16* wpb, __bf16* w3b) {
    int tid = blockIdx.x * blockDim.x + threadIdx.x;
    int stride = gridDim.x * blockDim.x;
    auto seg = [&](const float* __restrict__ s, __bf16* __restrict__ d, int n4) {
        const float4* s4 = (const float4*)s;
        uint2* d4 = (uint2*)d;
        for (int i = tid; i < n4; i += stride) {
            float4 v = s4[i];
            union { __bf16 h[4]; uint2 u; } o;
            o.h[0] = (__bf16)v.x; o.h[1] = (__bf16)v.y;
            o.h[2] = (__bf16)v.z; o.h[3] = (__bf16)v.w;
            d4[i] = o.u;
        }
    };
    seg(x,  xbf, N_TOK*DDIM/4);
    seg(w1, w1b, NGE*HDIM*DDIM/4);
    seg(w2, w2b, NGE*HDIM*HDIM/4);
    seg(wp, wpb, NGE*HDIM*DDIM/4);
    seg(w3, w3b, NGE*ODIM*HDIM/4);
}

// ---------------- routing: block-aggregated atomics ----------------
__global__ __launch_bounds__(256) void routing_k(
        const float* __restrict__ x,  const float* __restrict__ Wm,
        const float* __restrict__ bm, const float* __restrict__ Wr,
        const float* __restrict__ br,
        float* pmsum, float* psum, int* cnt, int* ecount,
        int* elist, float* wslot) {
    __shared__ float lpm[NG];
    __shared__ float lpsum[NGE];
    __shared__ int   lcnt[NG];
    __shared__ int   lec[NGE];
    __shared__ int   lbase[NGE];
    __shared__ int   lentry[NGE][64];

    int tid = threadIdx.x;
    if (tid < NG)  { lpm[tid] = 0.f; lcnt[tid] = 0; }
    if (tid < NGE) { lpsum[tid] = 0.f; lec[tid] = 0; }
    __syncthreads();

    int wid = tid >> 6, lane = tid & 63;

    #pragma unroll 1
    for (int i = 0; i < 16; ++i) {
        int t = blockIdx.x * 64 + i * 4 + wid;

        const float4* xr = (const float4*)(x + (size_t)t * DDIM);
        float4 xa = xr[lane*2], xb = xr[lane*2+1];

        float meta[NG];
        #pragma unroll
        for (int gi = 0; gi < NG; ++gi) {
            const float4* w = (const float4*)(Wm + gi*DDIM);
            float4 wa = w[lane*2], wb = w[lane*2+1];
            float s = xa.x*wa.x + xa.y*wa.y + xa.z*wa.z + xa.w*wa.w
                    + xb.x*wb.x + xb.y*wb.y + xb.z*wb.z + xb.w*wb.w;
            #pragma unroll
            for (int off = 32; off > 0; off >>= 1) s += __shfl_xor(s, off);
            meta[gi] = s + bm[gi];
        }
        int g = 0;
        if (meta[1] > meta[g]) g = 1;
        if (meta[2] > meta[g]) g = 2;

        float mm = fmaxf(meta[0], fmaxf(meta[1], meta[2]));
        float e0 = expf(meta[0]-mm), e1 = expf(meta[1]-mm), e2 = expf(meta[2]-mm);
        float inv = 1.f / (e0 + e1 + e2);

        float sel[NE];
        #pragma unroll
        for (int e = 0; e < NE; ++e) {
            const float4* w = (const float4*)(Wr + (size_t)(g*NE + e)*DDIM);
            float4 wa = w[lane*2], wb = w[lane*2+1];
            float s = xa.x*wa.x + xa.y*wa.y + xa.z*wa.z + xa.w*wa.w
                    + xb.x*wb.x + xb.y*wb.y + xb.z*wb.z + xb.w*wb.w;
            #pragma unroll
            for (int off = 32; off > 0; off >>= 1) s += __shfl_xor(s, off);
            sel[e] = s + br[g*NE + e];
        }
        float ms = fmaxf(fmaxf(sel[0],sel[1]), fmaxf(sel[2],sel[3]));
        float pe[NE]; float ss = 0.f;
        #pragma unroll
        for (int e = 0; e < NE; ++e) { pe[e] = expf(sel[e]-ms); ss += pe[e]; }
        float invs = 1.f / ss;

        int i0 = 0;
        #pragma unroll
        for (int e = 1; e < NE; ++e) if (sel[e] > sel[i0]) i0 = e;
        int i1 = (i0 == 0) ? 1 : 0;
        #pragma unroll
        for (int e = 0; e < NE; ++e) if (e != i0 && sel[e] > sel[i1]) i1 = e;
        float ew = expf(sel[i1] - sel[i0]);
        float wden = 1.f / (1.f + ew);

        if (lane == 0) {
            atomicAdd(&lpm[0], e0*inv);
            atomicAdd(&lpm[1], e1*inv);
            atomicAdd(&lpm[2], e2*inv);
            #pragma unroll
            for (int e = 0; e < NE; ++e) atomicAdd(&lpsum[g*NE + e], pe[e]*invs);
            atomicAdd(&lcnt[g], 1);
            int ee0 = g*NE + i0, ee1 = g*NE + i1;
            int p0 = atomicAdd(&lec[ee0], 1);
            lentry[ee0][p0] = t*2;
            int p1 = atomicAdd(&lec[ee1], 1);
            lentry[ee1][p1] = t*2 + 1;
            wslot[t*2]   = wden;
            wslot[t*2+1] = ew * wden;
        }
    }
    __syncthreads();

    if (tid < NG)  { atomicAdd(pmsum + tid, lpm[tid]); atomicAdd(cnt + tid, lcnt[tid]); }
    if (tid < NGE) { atomicAdd(psum + tid, lpsum[tid]);
                     lbase[tid] = atomicAdd(ecount + tid, lec[tid]); }
    __syncthreads();

    for (int e = wid; e < NGE; e += 4) {
        int c = lec[e], base = lbase[e];
        for (int j = lane; j < c; j += 64)
            elist[e*N_TOK + base + j] = lentry[e][j];
    }
}

// ---------------- aux scalar + task list (BM=64 tiles) ----------------
__global__ void finalize_aux_k(const float* pmsum, const float* psum, const int* cnt,
                               const int* ecount, int2* tasks, int* ntasks,
                               float* outAux) {
    if (threadIdx.x != 0 || blockIdx.x != 0) return;
    float s = 0.f;
    for (int i = 0; i < NG; ++i) { float p = pmsum[i] / (float)N_TOK; s += p*p; }
    float aux = 0.01f * NG * s;
    for (int gg = 0; gg < NG; ++gg) {
        int c = cnt[gg];
        if (c > 0) {
            float s2 = 0.f;
            for (int e = 0; e < NE; ++e) { float m = psum[gg*NE+e] / (float)c; s2 += m*m; }
            aux += 0.01f * NE * s2;
        }
    }
    *outAux = aux;
    int nt = 0;
    for (int ge = 0; ge < NGE; ++ge) {
        int c = ecount[ge];
        for (int m0 = 0; m0 < c; m0 += 64) tasks[nt++] = make_int2(ge, m0);
    }
    *ntasks = nt;
}

// ---------------- fused expert kernel ----------------
// One block = 64 expert-entries, full chain h -> u -> y with h/u resident in
// LDS (never touching HBM). 8 waves x 512 threads; per phase a wave owns a
// 128-col (phase1/2) or 64-col (phase3) n-slice of ALL 64 rows.
// K-loops are barrier-free: A from LDS (XOR-swizzled granule, conflict-free)
// or gathered-x global; B streamed global->register (row-major [out][in]
// matches the verified B-frag addressing: lane lr -> row, lg -> k-granule).
// Bijective XCD-chunked task map keeps one expert's ~5 MB weights L2-hot.
__global__ __launch_bounds__(512, 2) void fused_expert_k(
        const __bf16* __restrict__ xbf,
        const __bf16* __restrict__ w1b, const __bf16* __restrict__ w2b,
        const __bf16* __restrict__ wpb, const __bf16* __restrict__ w3b,
        const float* __restrict__ b1, const float* __restrict__ b2,
        const float* __restrict__ bp, const float* __restrict__ b3,
        __bf16* __restrict__ Y,
        const int* __restrict__ ecount, const int* __restrict__ elist,
        const int2* __restrict__ tasks, const int* __restrict__ ntasks) {
    __shared__ __align__(16) char hbuf[64 * 2048];   // h/u: [64 rows][1024 cols] bf16, swizzled
    __shared__ int ents[64];

    int T = *ntasks;
    int q = T >> 3, r = T & 7;
    int xcd = blockIdx.x & 7, idx = blockIdx.x >> 3;
    int pc = (xcd < r) ? q + 1 : q;
    if (idx >= pc) return;
    int task = ((xcd < r) ? xcd * (q + 1) : r * (q + 1) + (xcd - r) * q) + idx;
    int2 tk = tasks[task];
    int ge = tk.x, m0 = tk.y;
    int cntE = ecount[ge];

    int tid = threadIdx.x;
    if (tid < 64) {
        int rr = m0 + tid;
        if (rr >= cntE) rr = cntE - 1;
        ents[tid] = elist[ge*N_TOK + rr];
    }
    __syncthreads();

    int lane = tid & 63, wv = tid >> 6;
    int lr = lane & 15, lg = lane >> 4;

    // gathered-x row pointers for the 4 m-frags (lane lr picks row within frag)
    const char* px[4];
    #pragma unroll
    for (int mi = 0; mi < 4; ++mi)
        px[mi] = (const char*)xbf + (size_t)(ents[mi*16 + lr] >> 1) * (DDIM*2) + lg*16;

    // swizzled LDS address for [row][k-granule g]: spreads 16-row column reads
    auto lds_at = [&](int row, int g) -> char* {
        return hbuf + row*2048 + (((g ^ (row & 7)) << 4));
    };

    f32x4 acc[4][8];

    // ======== phase 1: h = relu(x W1^T + b1), wave cols wv*128..+127 ========
    #pragma unroll
    for (int mi = 0; mi < 4; ++mi)
        #pragma unroll
        for (int ni = 0; ni < 8; ++ni) acc[mi][ni] = (f32x4){0.f,0.f,0.f,0.f};
    {
        const char* pb[8];
        #pragma unroll
        for (int ni = 0; ni < 8; ++ni)
            pb[ni] = (const char*)w1b + ((size_t)ge*HDIM + wv*128 + ni*16 + lr) * (DDIM*2) + lg*16;
        #pragma unroll 2
        for (int k0 = 0; k0 < DDIM; k0 += 32) {
            bf16x8 av[4], bv[8];
            #pragma unroll
            for (int mi = 0; mi < 4; ++mi) av[mi] = *(const bf16x8*)(px[mi] + k0*2);
            #pragma unroll
            for (int ni = 0; ni < 8; ++ni) bv[ni] = *(const bf16x8*)(pb[ni] + k0*2);
            #pragma unroll
            for (int mi = 0; mi < 4; ++mi)
                #pragma unroll
                for (int ni = 0; ni < 8; ++ni)
                    acc[mi][ni] = __builtin_amdgcn_mfma_f32_16x16x32_bf16(
                        av[mi], bv[ni], acc[mi][ni], 0, 0, 0);
        }
    }
    // write h to LDS (C-layout: col = ni*16+lr, row = mi*16+lg*4+j)
    #pragma unroll
    for (int ni = 0; ni < 8; ++ni) {
        int col = wv*128 + ni*16 + lr;
        float bb = b1[(size_t)ge*HDIM + col];
        int g = col >> 3, cb = (col & 7) * 2;
        #pragma unroll
        for (int mi = 0; mi < 4; ++mi)
            #pragma unroll
            for (int j = 0; j < 4; ++j) {
                int row = mi*16 + lg*4 + j;
                float v = fmaxf(acc[mi][ni][j] + bb, 0.f);
                *(__bf16*)(hbuf + row*2048 + (((g ^ (row & 7)) << 4) | cb)) = (__bf16)v;
            }
    }
    __syncthreads();

    // ======== phase 2: u = relu(h W2^T + x Wp^T + b2 + bp) ========
    #pragma unroll
    for (int mi = 0; mi < 4; ++mi)
        #pragma unroll
        for (int ni = 0; ni < 8; ++ni) acc[mi][ni] = (f32x4){0.f,0.f,0.f,0.f};
    {
        const char* pb[8];
        #pragma unroll
        for (int ni = 0; ni < 8; ++ni)
            pb[ni] = (const char*)w2b + ((size_t)ge*HDIM + wv*128 + ni*16 + lr) * (HDIM*2) + lg*16;
        #pragma unroll 2
        for (int k0 = 0; k0 < HDIM; k0 += 32) {
            bf16x8 av[4], bv[8];
            #pragma unroll
            for (int mi = 0; mi < 4; ++mi) {
                int row = mi*16 + lr;
                av[mi] = *(const bf16x8*)lds_at(row, (k0 >> 3) + lg);
            }
            #pragma unroll
            for (int ni = 0; ni < 8; ++ni) bv[ni] = *(const bf16x8*)(pb[ni] + k0*2);
            #pragma unroll
            for (int mi = 0; mi < 4; ++mi)
                #pragma unroll
                for (int ni = 0; ni < 8; ++ni)
                    acc[mi][ni] = __builtin_amdgcn_mfma_f32_16x16x32_bf16(
                        av[mi], bv[ni], acc[mi][ni], 0, 0, 0);
        }
        const char* pw[8];
        #pragma unroll
        for (int ni = 0; ni < 8; ++ni)
            pw[ni] = (const char*)wpb + ((size_t)ge*HDIM + wv*128 + ni*16 + lr) * (DDIM*2) + lg*16;
        #pragma unroll 2
        for (int k0 = 0; k0 < DDIM; k0 += 32) {
            bf16x8 av[4], bv[8];
            #pragma unroll
            for (int mi = 0; mi < 4; ++mi) av[mi] = *(const bf16x8*)(px[mi] + k0*2);
            #pragma unroll
            for (int ni = 0; ni < 8; ++ni) bv[ni] = *(const bf16x8*)(pw[ni] + k0*2);
            #pragma unroll
            for (int mi = 0; mi < 4; ++mi)
                #pragma unroll
                for (int ni = 0; ni < 8; ++ni)
                    acc[mi][ni] = __builtin_amdgcn_mfma_f32_16x16x32_bf16(
                        av[mi], bv[ni], acc[mi][ni], 0, 0, 0);
        }
    }
    __syncthreads();          // all h reads done before overwrite
    #pragma unroll
    for (int ni = 0; ni < 8; ++ni) {
        int col = wv*128 + ni*16 + lr;
        float bb = b2[(size_t)ge*HDIM + col] + bp[(size_t)ge*HDIM + col];
        int g = col >> 3, cb = (col & 7) * 2;
        #pragma unroll
        for (int mi = 0; mi < 4; ++mi)
            #pragma unroll
            for (int j = 0; j < 4; ++j) {
                int row = mi*16 + lg*4 + j;
                float v = fmaxf(acc[mi][ni][j] + bb, 0.f);
                *(__bf16*)(hbuf + row*2048 + (((g ^ (row & 7)) << 4) | cb)) = (__bf16)v;
            }
    }
    __syncthreads();

    // ======== phase 3: y = u W3^T + b3, wave cols wv*64..+63 of ODIM ========
    f32x4 acc3[4][4];
    #pragma unroll
    for (int mi = 0; mi < 4; ++mi)
        #pragma unroll
        for (int ni = 0; ni < 4; ++ni) acc3[mi][ni] = (f32x4){0.f,0.f,0.f,0.f};
    {
        const char* pb[4];
        #pragma unroll
        for (int ni = 0; ni < 4; ++ni)
            pb[ni] = (const char*)w3b + ((size_t)ge*ODIM + wv*64 + ni*16 + lr) * (HDIM*2) + lg*16;
        #pragma unroll 2
        for (int k0 = 0; k0 < HDIM; k0 += 32) {
            bf16x8 av[4], bv[4];
            #pragma unroll
            for (int mi = 0; mi < 4; ++mi) {
                int row = mi*16 + lr;
                av[mi] = *(const bf16x8*)lds_at(row, (k0 >> 3) + lg);
            }
            #pragma unroll
            for (int ni = 0; ni < 4; ++ni) bv[ni] = *(const bf16x8*)(pb[ni] + k0*2);
            #pragma unroll
            for (int mi = 0; mi < 4; ++mi)
                #pragma unroll
                for (int ni = 0; ni < 4; ++ni)
                    acc3[mi][ni] = __builtin_amdgcn_mfma_f32_16x16x32_bf16(
                        av[mi], bv[ni], acc3[mi][ni], 0, 0, 0);
        }
    }
    // scatter y to Y[entry][col]
    #pragma unroll
    for (int ni = 0; ni < 4; ++ni) {
        int col = wv*64 + ni*16 + lr;
        float bb = b3[(size_t)ge*ODIM + col];
        #pragma unroll
        for (int mi = 0; mi < 4; ++mi)
            #pragma unroll
            for (int j = 0; j < 4; ++j) {
                int rloc = mi*16 + lg*4 + j;
                if (m0 + rloc < cntE)
                    Y[(size_t)ents[rloc] * ODIM + col] = (__bf16)(acc3[mi][ni][j] + bb);
            }
    }
}

// ---------------- combine: out[t] = w0*Y[2t] + w1*Y[2t+1] ----------------
__global__ void combine_k(const __bf16* __restrict__ Y, const float* __restrict__ wslot,
                          float* __restrict__ out) {
    int idx = blockIdx.x * blockDim.x + threadIdx.x;
    int t = idx >> 6;
    int o = (idx & 63) * 8;
    bf16x8 y0 = *(const bf16x8*)(Y + (size_t)(2*t)   * ODIM + o);
    bf16x8 y1 = *(const bf16x8*)(Y + (size_t)(2*t+1) * ODIM + o);
    float w0 = wslot[2*t], w1 = wslot[2*t+1];
    float4 r0, r1;
    r0.x = w0*(float)y0[0] + w1*(float)y1[0];
    r0.y = w0*(float)y0[1] + w1*(float)y1[1];
    r0.z = w0*(float)y0[2] + w1*(float)y1[2];
    r0.w = w0*(float)y0[3] + w1*(float)y1[3];
    r1.x = w0*(float)y0[4] + w1*(float)y1[4];
    r1.y = w0*(float)y0[5] + w1*(float)y1[5];
    r1.z = w0*(float)y0[6] + w1*(float)y1[6];
    r1.w = w0*(float)y0[7] + w1*(float)y1[7];
    float* op = out + (size_t)t * ODIM + o;
    ((float4*)op)[0] = r0;
    ((float4*)op)[1] = r1;
}

extern "C" void kernel_launch(void* const* d_in, const int* in_sizes, int n_in,
                              void* d_out, int out_size, void* d_ws, size_t ws_size,
                              hipStream_t stream) {
    const float* x  = (const float*)d_in[0];
    const float* Wm = (const float*)d_in[1];
    const float* bm = (const float*)d_in[2];
    const float* Wr = (const float*)d_in[3];
    const float* br = (const float*)d_in[4];
    const float* W1 = (const float*)d_in[5];
    const float* b1 = (const float*)d_in[6];
    const float* W2 = (const float*)d_in[7];
    const float* b2 = (const float*)d_in[8];
    const float* Wp = (const float*)d_in[9];
    const float* bp = (const float*)d_in[10];
    const float* W3 = (const float*)d_in[11];
    const float* b3 = (const float*)d_in[12];

    if (ws_size < WS_NEED) return;

    char* ws = (char*)d_ws;
    float* outp = (float*)d_out;

    float* pmsum  = (float*)ws;
    float* psum   = (float*)ws + 4;
    int*   cnt    = (int*)ws + 16;
    int*   ecount = (int*)ws + 20;
    int*   ntasks = (int*)ws + 34;
    float* wslot  = (float*)(ws + OFF_WSLOT);
    int*   elist  = (int*)(ws + OFF_ELIST);
    int2*  tasks  = (int2*)(ws + OFF_TASK);
    __bf16* xbf = (__bf16*)(ws + OFF_XBF);
    __bf16* w1b = (__bf16*)(ws + OFF_W1);
    __bf16* w2b = (__bf16*)(ws + OFF_W2);
    __bf16* wpb = (__bf16*)(ws + OFF_WP);
    __bf16* w3b = (__bf16*)(ws + OFF_W3);
    __bf16* Y   = (__bf16*)(ws + OFF_Y);

    hipMemsetAsync(d_ws, 0, 512, stream);

    cast_all_k<<<4096, 256, 0, stream>>>(x, W1, W2, Wp, W3, xbf, w1b, w2b, wpb, w3b);

    routing_k<<<256, 256, 0, stream>>>(x, Wm, bm, Wr, br,
                                       pmsum, psum, cnt, ecount, elist, wslot);

    finalize_aux_k<<<1, 64, 0, stream>>>(pmsum, psum, cnt, ecount, tasks, ntasks,
                                         outp + (size_t)N_TOK*ODIM);

    fused_expert_k<<<TASK_CAP, 512, 0, stream>>>(
        xbf, w1b, w2b, wpb, w3b, b1, b2, bp, b3, Y,
        ecount, elist, tasks, ntasks);

    combine_k<<<4096, 256, 0, stream>>>(Y, wslot, outp);
}